// Round 1
// baseline (441.617 us; speedup 1.0000x reference)
//
#include <hip/hip_runtime.h>
#include <hip/hip_fp16.h>

namespace {
constexpr int kT = 32, kDQ = 128, kK = 8, kS = 4, kCTX = 16, kD = 257, kEVO = 8;
constexpr float kDT = 0.2f, kDAMP = 0.1f, kGAMMA = 10.0f, kEPS = 1e-8f;

typedef _Float16 h2 __attribute__((ext_vector_type(2)));

__device__ __forceinline__ float dot2h(unsigned a, unsigned b, float c) {
#if __has_builtin(__builtin_amdgcn_fdot2)
  return __builtin_amdgcn_fdot2(__builtin_bit_cast(h2, a), __builtin_bit_cast(h2, b), c, false);
#else
  h2 ha = __builtin_bit_cast(h2, a), hb = __builtin_bit_cast(h2, b);
  return c + (float)ha.x * (float)hb.x + (float)ha.y * (float)hb.y;
#endif
}

__device__ __forceinline__ unsigned packh2(float lo, float hi) {
  __half l = __float2half(lo), h = __float2half(hi);
  return (unsigned)__half_as_ushort(l) | ((unsigned)__half_as_ushort(h) << 16);
}
}  // namespace

extern "C" __global__ void __launch_bounds__(1024)
seq_main(const int* __restrict__ inputs, const int* __restrict__ targets,
         const int* __restrict__ task_ids, const float* __restrict__ st0,
         const float* __restrict__ bit_emb, const float* __restrict__ task_u,
         const float* __restrict__ ctx_emb, const float* __restrict__ rw_g,
         const float* __restrict__ rb_g, const float* __restrict__ Wq_g,
         const float* __restrict__ Wc_g, const float* __restrict__ b_g,
         const float* __restrict__ A_g, float* __restrict__ ws) {
  const int tid = threadIdx.x;
  const int b = blockIdx.x;
  const int kq = tid >> 7, iq = tid & 127;  // (k,i) ownership of A row

  __shared__ __align__(16) float q_l[kDQ];
  __shared__ __align__(16) float p_l[kDQ];
  __shared__ __align__(16) float u4_l[4][kDQ];
  __shared__ __align__(16) unsigned tq_l[kDQ / 2];   // tanh(q) packed half2
  __shared__ __align__(16) float Ybuf[kK][kDQ];
  __shared__ __align__(16) float Wq_l[kK][kDQ];      // transposed: [k][j]
  __shared__ float wq_ctx2[2][kK];                   // ctx@Wc+b per task
  __shared__ float wlog_l[kK];                       // q@Wq of current q
  __shared__ float w_l[kK];                          // softmax weights of this evo step
  __shared__ float chartw_l[kK];                     // w at evo step 7
  __shared__ float rw_l[kK * kS * kD];               // readout weight (32 x 257)
  __shared__ float rb_l[kK * kS];
  __shared__ float lk_l[kK * kS];                    // logits_k
  __shared__ float acc_l[64];
  __shared__ float s_l;

  // ---------- load phase ----------
  for (int idx = tid; idx < kK * kS * kD; idx += 1024) rw_l[idx] = rw_g[idx];
  if (tid < kDQ * kK) { int j = tid >> 3, kk = tid & 7; Wq_l[kk][j] = Wq_g[tid]; }
  if (tid < kK * kS) rb_l[tid] = rb_g[tid];
  if (tid < kDQ) { q_l[tid] = st0[b * kD + tid]; p_l[tid] = st0[b * kD + kDQ + tid]; }
  if (tid == 0) s_l = st0[b * kD + 2 * kDQ];
  if (tid < 64) acc_l[tid] = 0.f;
  if (tid < 512) {  // u for 4 (task,bit) combos
    int cb = tid >> 7, i = tid & 127;
    u4_l[cb][i] = tanhf(bit_emb[(cb & 1) * kDQ + i]) + tanhf(task_u[(cb >> 1) * kDQ + i]);
  }
  if (tid < 16) {  // ctx@Wc + b per task
    int tk = tid >> 3, kk = tid & 7;
    float s = b_g[kk];
    #pragma unroll
    for (int c = 0; c < kCTX; c++) s += tanhf(ctx_emb[tk * kCTX + c]) * Wc_g[c * kK + kk];
    wq_ctx2[tk][kk] = s;
  }
  // A row (k,i) into registers as packed fp16 pairs (j, j+1)
  unsigned a_[64];
  {
    const float4* Arow = reinterpret_cast<const float4*>(A_g + ((size_t)(kq * kDQ + iq)) * kDQ);
    #pragma unroll
    for (int jj = 0; jj < 32; jj++) {
      float4 f = Arow[jj];
      a_[2 * jj] = packh2(f.x, f.y);
      a_[2 * jj + 1] = packh2(f.z, f.w);
    }
  }
  __syncthreads();

  // initial tq and initial router q-logits
  if (tid < kDQ) {
    float tv = tanhf(q_l[tid]);
    float to = __shfl_xor(tv, 1);
    if (!(tid & 1)) tq_l[tid >> 1] = packh2(tv, to);
  }
  if (tid < 512) {
    int kk = tid >> 6, l = tid & 63;
    float2 qp = reinterpret_cast<const float2*>(q_l)[l];
    float2 wp = reinterpret_cast<const float2*>(&Wq_l[kk][0])[l];
    float part = qp.x * wp.x + qp.y * wp.y;
    part += __shfl_xor(part, 1);  part += __shfl_xor(part, 2);
    part += __shfl_xor(part, 4);  part += __shfl_xor(part, 8);
    part += __shfl_xor(part, 16); part += __shfl_xor(part, 32);
    if (l == 0) wlog_l[kk] = part;
  }
  __syncthreads();

  const int boff = b * kT;
  for (int t = 0; t < kT; t++) {
    const int bit = inputs[boff + t];
    const int task = task_ids[boff + t];
    const int uix = task * 2 + bit;

    for (int e = 0; e < kEVO; e++) {
      // ---- Phase B: softmax (8 lanes, hidden) + A-row dots (all threads) ----
      if (tid < kK) {
        float myl = wlog_l[tid] + wq_ctx2[task][tid];
        float mx = myl;
        #pragma unroll
        for (int kk = 0; kk < kK; kk++) mx = fmaxf(mx, wlog_l[kk] + wq_ctx2[task][kk]);
        float ev = expf(myl - mx);
        float sm = ev;
        sm += __shfl_xor(sm, 1); sm += __shfl_xor(sm, 2); sm += __shfl_xor(sm, 4);
        w_l[tid] = ev / sm;
      }
      float y = 0.f;
      {
        const uint4* tq4 = reinterpret_cast<const uint4*>(tq_l);
        #pragma unroll
        for (int jj = 0; jj < 16; jj++) {
          uint4 tt = tq4[jj];  // broadcast LDS read (same addr all lanes)
          y = dot2h(a_[4 * jj + 0], tt.x, y);
          y = dot2h(a_[4 * jj + 1], tt.y, y);
          y = dot2h(a_[4 * jj + 2], tt.z, y);
          y = dot2h(a_[4 * jj + 3], tt.w, y);
        }
      }
      Ybuf[kq][iq] = y;
      __syncthreads();
      // ---- Phase C1: force, state update, tq repack ----
      if (tid < kDQ) {
        float f = 0.f;
        #pragma unroll
        for (int kk = 0; kk < kK; kk++) f += w_l[kk] * Ybuf[kk][tid];
        float pv = (1.f - kDT * kDAMP) * p_l[tid] + kDT * (f + u4_l[uix][tid]);
        float qv = q_l[tid] + kDT * tanhf(pv);
        p_l[tid] = pv; q_l[tid] = qv;
        float tv = tanhf(qv);
        float to = __shfl_xor(tv, 1);
        if (!(tid & 1)) tq_l[tid >> 1] = packh2(tv, to);
        if (e == kEVO - 1 && tid < kK) chartw_l[tid] = w_l[tid];
      }
      __syncthreads();
      // ---- Phase C2: router q-logits for new q (8 waves, one k each) ----
      if (tid < 512) {
        int kk = tid >> 6, l = tid & 63;
        float2 qp = reinterpret_cast<const float2*>(q_l)[l];
        float2 wp = reinterpret_cast<const float2*>(&Wq_l[kk][0])[l];
        float part = qp.x * wp.x + qp.y * wp.y;
        part += __shfl_xor(part, 1);  part += __shfl_xor(part, 2);
        part += __shfl_xor(part, 4);  part += __shfl_xor(part, 8);
        part += __shfl_xor(part, 16); part += __shfl_xor(part, 32);
        if (l == 0) wlog_l[kk] = part;
      }
      __syncthreads();
    }

    // ---- decode: logits_k[pair] = state . rw[pair] (+rb), 32 groups of 32 lanes ----
    {
      int pair = tid >> 5, ln = tid & 31;
      const float* rwrow = &rw_l[pair * kD];
      float sacc = 0.f;
      #pragma unroll
      for (int m = 0; m < 8; m++) {
        int d = ln + 32 * m;
        float sv = (m < 4) ? q_l[d] : p_l[d - kDQ];
        sacc += sv * rwrow[d];
      }
      if (ln == 0) sacc += s_l * rwrow[256];
      sacc += __shfl_xor(sacc, 1); sacc += __shfl_xor(sacc, 2);
      sacc += __shfl_xor(sacc, 4); sacc += __shfl_xor(sacc, 8);
      sacc += __shfl_xor(sacc, 16);
      if (ln == 0) lk_l[pair] = sacc + rb_l[pair];
    }
    __syncthreads();
    // ---- scalar tail: top-2 mix, losses, accumulators ----
    if (tid == 0) {
      const int tgt = targets[boff + t];
      const int prv = (t == 0) ? 0 : targets[boff + t - 1];
      float lg[kK]; float mx = -1e30f;
      #pragma unroll
      for (int kk = 0; kk < kK; kk++) { lg[kk] = wlog_l[kk] + wq_ctx2[task][kk]; mx = fmaxf(mx, lg[kk]); }
      float cw[kK]; float ssum = 0.f;
      #pragma unroll
      for (int kk = 0; kk < kK; kk++) { cw[kk] = expf(lg[kk] - mx); ssum += cw[kk]; }
      float invs = 1.f / ssum;
      #pragma unroll
      for (int kk = 0; kk < kK; kk++) cw[kk] *= invs;
      // top-2 with first-occurrence tie-break (lax.top_k semantics)
      int i0 = 0; float v0 = cw[0];
      #pragma unroll
      for (int kk = 1; kk < kK; kk++) if (cw[kk] > v0) { v0 = cw[kk]; i0 = kk; }
      int i1 = (i0 == 0) ? 1 : 0; float v1 = cw[i1];
      #pragma unroll
      for (int kk = 0; kk < kK; kk++) if (kk != i0 && cw[kk] > v1) { v1 = cw[kk]; i1 = kk; }
      float wsum = fmaxf(v0 + v1, kEPS);
      float wn0 = v0 / wsum, wn1 = v1 / wsum;
      float lg4[4];
      #pragma unroll
      for (int v = 0; v < 4; v++) lg4[v] = wn0 * lk_l[i0 * 4 + v] + wn1 * lk_l[i1 * 4 + v];
      float m2 = fmaxf(lg4[0], lg4[1]);
      float lse2 = m2 + logf(expf(lg4[0] - m2) + expf(lg4[1] - m2));
      float m4 = fmaxf(fmaxf(lg4[0], lg4[1]), fmaxf(lg4[2], lg4[3]));
      float lse4 = m4 + logf(expf(lg4[0] - m4) + expf(lg4[1] - m4) + expf(lg4[2] - m4) + expf(lg4[3] - m4));
      int idx2 = (tgt < 1) ? tgt : 1;  // JAX clamps OOB gather on logits2
      float p2 = (idx2 == 0) ? lg4[0] : lg4[1];
      float p4 = (tgt == 0) ? lg4[0] : ((tgt == 1) ? lg4[1] : ((tgt == 2) ? lg4[2] : lg4[3]));
      float ce2 = lse2 - p2, ce4 = lse4 - p4;
      float pe = (task == 0) ? ce2 : ce4;
      int pred;
      if (task == 0) pred = (lg4[1] > lg4[0]) ? 1 : 0;
      else {
        pred = 0; float bv = lg4[0];
        if (lg4[1] > bv) { bv = lg4[1]; pred = 1; }
        if (lg4[2] > bv) { bv = lg4[2]; pred = 2; }
        if (lg4[3] > bv) { bv = lg4[3]; pred = 3; }
      }
      float corr = (pred == tgt) ? 1.f : 0.f;
      float csl = -logf(fmaxf(chartw_l[prv], kEPS));
      float Ft = kGAMMA * (pe + csl);
      acc_l[0] += Ft; acc_l[1] += corr; acc_l[2] += pe;
      #pragma unroll
      for (int kk = 0; kk < kK; kk++) acc_l[3 + kk] += chartw_l[kk];
      acc_l[11 + task] += corr; acc_l[13 + task] += 1.f;
      if (task == 1) {
        #pragma unroll
        for (int kk = 0; kk < kK; kk++) acc_l[15 + prv * kK + kk] += chartw_l[kk];
        acc_l[47 + prv] += 1.f;
      }
    }
    __syncthreads();
  }

  __syncthreads();
  if (tid < 64) ws[b * 64 + tid] = acc_l[tid];
}

extern "C" __global__ void seq_finalize(const float* __restrict__ ws, float* __restrict__ out) {
  const int tid = threadIdx.x;
  __shared__ float red[51];
  if (tid < 51) {
    float s = 0.f;
    for (int b = 0; b < 256; b++) s += ws[b * 64 + tid];
    red[tid] = s;
  }
  __syncthreads();
  if (tid == 0) {
    const float BT = 256.f * 32.f;
    out[0] = red[0] / BT;        // mean_F
    out[1] = red[1] / BT;        // mean_acc
    out[2] = red[2] / BT;        // mean_ce
    float us = 0.f;
    for (int k = 0; k < 8; k++) { out[3 + k] = red[3 + k]; us += red[3 + k]; }
    float ent = 0.f;
    for (int k = 0; k < 8; k++) {
      float dist = red[3 + k] / (us + kEPS);
      ent -= dist * logf(dist + kEPS);
    }
    out[11] = ent;
    out[12] = red[11] / (red[13] + kEPS);
    out[13] = red[12] / (red[14] + kEPS);
    float tot = 0.f;
    for (int j = 0; j < 32; j++) { out[14 + j] = red[15 + j]; tot += red[15 + j]; }
    for (int s2 = 0; s2 < 4; s2++) out[46 + s2] = red[47 + s2];
    float inv = 1.f / (tot + kEPS);
    float ps[4] = {0.f, 0.f, 0.f, 0.f};
    float pc[8] = {0.f, 0.f, 0.f, 0.f, 0.f, 0.f, 0.f, 0.f};
    for (int s2 = 0; s2 < 4; s2++)
      for (int k = 0; k < 8; k++) {
        float jv = red[15 + s2 * 8 + k] * inv;
        ps[s2] += jv; pc[k] += jv;
      }
    float mi = 0.f;
    for (int s2 = 0; s2 < 4; s2++)
      for (int k = 0; k < 8; k++) {
        float jv = red[15 + s2 * 8 + k] * inv;
        mi += jv * (logf(jv + kEPS) - logf(ps[s2] + kEPS) - logf(pc[k] + kEPS));
      }
    mi = (tot > 0.f) ? fmaxf(mi, 0.f) : 0.f;
    out[50] = mi;
  }
}

extern "C" void kernel_launch(void* const* d_in, const int* in_sizes, int n_in,
                              void* d_out, int out_size, void* d_ws, size_t ws_size,
                              hipStream_t stream) {
  (void)in_sizes; (void)n_in; (void)out_size; (void)ws_size;
  const int* inputs   = (const int*)d_in[0];
  const int* targets  = (const int*)d_in[1];
  const int* task_ids = (const int*)d_in[2];
  const float* st0      = (const float*)d_in[3];
  const float* bit_emb  = (const float*)d_in[4];
  const float* task_u   = (const float*)d_in[5];
  const float* ctx_emb  = (const float*)d_in[6];
  const float* rw       = (const float*)d_in[7];
  const float* rb       = (const float*)d_in[8];
  const float* Wq       = (const float*)d_in[9];
  const float* Wc       = (const float*)d_in[10];
  const float* bb       = (const float*)d_in[11];
  const float* A        = (const float*)d_in[12];
  float* ws  = (float*)d_ws;
  float* out = (float*)d_out;
  hipLaunchKernelGGL(seq_main, dim3(256), dim3(1024), 0, stream,
                     inputs, targets, task_ids, st0, bit_emb, task_u, ctx_emb,
                     rw, rb, Wq, Wc, bb, A, ws);
  hipLaunchKernelGGL(seq_finalize, dim3(1), dim3(64), 0, stream, ws, out);
}